// Round 6
// baseline (220.431 us; speedup 1.0000x reference)
//
#include <hip/hip_runtime.h>
#include <math.h>

#define SCALE_L2E 0.51006972157f   // (1/sqrt(8)) * log2(e) -- softmax done in exp2 domain
#define EPSV 1e-5f

typedef __attribute__((ext_vector_type(8))) short bf16x8;
typedef __attribute__((ext_vector_type(4))) float f32x4;
typedef __attribute__((ext_vector_type(16))) float f32x16;
typedef __attribute__((ext_vector_type(4))) int i32x4;
typedef __attribute__((ext_vector_type(2))) int i32x2;

static __device__ __forceinline__ unsigned short bfh(float f) {
    return (unsigned short)(__builtin_bit_cast(unsigned int, f) >> 16);
}
static __device__ __forceinline__ int pack2(float lo, float hi) {
    return __builtin_amdgcn_perm(__builtin_bit_cast(unsigned int, hi),
                                 __builtin_bit_cast(unsigned int, lo), 0x07060302u);
}
#define LGKM0() __asm__ __volatile__("s_waitcnt lgkmcnt(0)" ::: "memory")
#define MFMA16(a, b, c) __builtin_amdgcn_mfma_f32_16x16x32_bf16((a), (b), (c), 0, 0, 0)

// ws layout: [0,8192) ushort wqk B-frags; [8192,40960) ushort W2ᵀ B-frags;
//            byte 81920: float bnA[64], bnB[64]
__global__ void prep_kernel(const float* __restrict__ w_qk,
                            const float* __restrict__ conv_w,
                            const float* __restrict__ conv_b,
                            const float* __restrict__ bn_g, const float* __restrict__ bn_b,
                            const float* __restrict__ bn_m, const float* __restrict__ bn_v,
                            unsigned short* __restrict__ ws) {
    int i = blockIdx.x * 256 + threadIdx.x;
    if (i < 8192) {
        int f = i >> 9, rem = i & 511, l = rem >> 3, j = rem & 7;
        int nt = f >> 1, ks = f & 1;
        int k = ks * 32 + (l >> 4) * 8 + j;
        int nn = nt * 16 + (l & 15);
        ws[i] = bfh(w_qk[k * 128 + nn]);
    } else if (i < 40960) {
        int i2 = i - 8192;
        int g = i2 >> 9, rem = i2 & 511, l = rem >> 3, j = rem & 7;
        int h = g >> 3, nt = (g >> 1) & 3, ks = g & 1;
        int c = ks * 32 + (l >> 4) * 8 + j;
        int o = nt * 16 + (l & 15);
        ws[i] = bfh(conv_w[h * 4096 + o * 64 + c]);
    } else if (i < 41024) {
        int o = i - 40960;
        float gv = bn_g[o] * rsqrtf(bn_v[o] + EPSV);
        float bb = bn_b[o] - bn_m[o] * gv;
        float cb = 0.f;
        for (int h = 0; h < 8; h++) cb += conv_b[h * 64 + o];
        float* wsf = (float*)(ws + 40960);
        wsf[o] = gv;
        wsf[64 + o] = bb + cb * gv;
    }
}

// R6: TWO (n,t) tiles per wave (adjacent t, same n), phase-interleaved in one
// instruction stream. Rationale (MEASURED r0-r5): dur pinned at ~98us across
// occupancy 20-40%, swizzles, wait-count 5->3 => limiter is the per-wave serial
// dependency chain with ~2 waves/SIMD resident. Two independent chains per wave
// give in-stream ILP that doesn't depend on co-residency; both tiles share every
// weight/topo fetch and every lgkmcnt(0).
// Per-wave LDS 18432 B = 2 x 9216 (tile B at +9216):
//   [0,4096):    qbuf[32][24]u16 @0 + kbuf @1536 (qk->dots), then FWT swizzled
//   [4096,9216): P0 [32][40]u16 @+0, P1 @+2560
// Block: 4 waves, 73728 B LDS -> 2 blocks/CU.
// VGPR: persistent 128 (xa/yna/acc x2) + ~45 transient. launch_bounds(256,1).
// Spill tripwire (MEASURED r1/r2): FETCH > 70 MB => scratch spill, revert.
__global__ __launch_bounds__(256, 1)
void sagc_kernel(const float* __restrict__ x,
                 const float* __restrict__ ln_g, const float* __restrict__ ln_b,
                 const float* __restrict__ b_qk,
                 const float* __restrict__ topo,
                 const unsigned short* __restrict__ ws,
                 float* __restrict__ out)
{
    __shared__ __align__(16) unsigned char smem[73728];
    const int tid = threadIdx.x;
    const int lane = tid & 63, wv = tid >> 6;
    const int l15 = lane & 15, quad = lane >> 4;
    const int r32 = lane & 31, hi = lane >> 5;

    unsigned char* my = smem + wv * 18432;
    // tile-A buffers (tile-B = same + 9216, folded into ds imm offsets)
    unsigned short* qbuf = (unsigned short*)my;            // [32][24] u16
    unsigned short* kbuf = (unsigned short*)(my + 1536);
    unsigned char*  fwb  = my;                             // FWT swizzled (overlays q/k)
    unsigned char*  pb0  = my + 4096;                      // P0 [32][40] u16
    unsigned char*  pb1  = my + 4096 + 2560;

    const unsigned short* wqk = ws;
    const unsigned short* w2f = ws + 8192;
    const float* bnA = (const float*)(ws + 40960);
    const float* bnB = bnA + 64;

    const int tileA = (blockIdx.x * 4 + wv) * 2;           // even; tileB = tileA+1, same n
    const int n = tileA >> 8, tA = tileA & 255;
    const float* xgA = x + (size_t)n * 409600 + (size_t)tA * 25;   // + c*6400 + v
    const float* xgB = xgA + 25;
    float* ogA = out + (size_t)n * 409600 + (size_t)tA * 25;
    float* ogB = ogA + 25;

    // ---- prologue per tile: x load -> xa frags + LN(shuffle) -> yn frags ----
    auto prologue = [&](const float* xg, bf16x8 (&xa)[2][2], bf16x8 (&yna)[2][2]) {
        float xf[2][2][8];
        #pragma unroll
        for (int mt = 0; mt < 2; mt++) {
            const int v = mt * 16 + l15;
            const bool ok = (v < 25);
            const float* xc = xg + v;
            #pragma unroll
            for (int ks = 0; ks < 2; ks++)
                #pragma unroll
                for (int j = 0; j < 8; j++) {
                    int c = ks * 32 + quad * 8 + j;
                    xf[mt][ks][j] = ok ? xc[c * 6400] : 0.f;
                }
        }
        float sum_[2] = {0.f, 0.f}, ssq_[2] = {0.f, 0.f};
        #pragma unroll
        for (int mt = 0; mt < 2; mt++)
            #pragma unroll
            for (int ks = 0; ks < 2; ks++) {
                i32x4 pa;
                #pragma unroll
                for (int q = 0; q < 4; q++)
                    pa[q] = pack2(xf[mt][ks][2 * q], xf[mt][ks][2 * q + 1]);
                xa[mt][ks] = __builtin_bit_cast(bf16x8, pa);
                #pragma unroll
                for (int j = 0; j < 8; j++) {
                    float a = xf[mt][ks][j];
                    sum_[mt] += a;
                    ssq_[mt] += a * a;
                }
            }
        float muv[2], rsv[2];
        #pragma unroll
        for (int mt = 0; mt < 2; mt++) {
            sum_[mt] += __shfl_xor(sum_[mt], 16);
            sum_[mt] += __shfl_xor(sum_[mt], 32);
            ssq_[mt] += __shfl_xor(ssq_[mt], 16);
            ssq_[mt] += __shfl_xor(ssq_[mt], 32);
            muv[mt] = sum_[mt] * 0.015625f;
            rsv[mt] = rsqrtf(ssq_[mt] * 0.015625f - muv[mt] * muv[mt] + EPSV);
        }
        #pragma unroll
        for (int ks = 0; ks < 2; ks++) {
            f32x4 ga = *(const f32x4*)&ln_g[ks * 32 + quad * 8];
            f32x4 gb = *(const f32x4*)&ln_g[ks * 32 + quad * 8 + 4];
            f32x4 ba = *(const f32x4*)&ln_b[ks * 32 + quad * 8];
            f32x4 bb = *(const f32x4*)&ln_b[ks * 32 + quad * 8 + 4];
            #pragma unroll
            for (int mt = 0; mt < 2; mt++) {
                float yv[8];
                #pragma unroll
                for (int j = 0; j < 8; j++) {
                    float g = (j < 4) ? ga[j] : gb[j - 4];
                    float bt = (j < 4) ? ba[j] : bb[j - 4];
                    // unpack from xf (still live) for exact-f32 LN
                    yv[j] = (xf[mt][ks][j] - muv[mt]) * rsv[mt] * g + bt;
                }
                i32x4 p;
                #pragma unroll
                for (int q = 0; q < 4; q++) p[q] = pack2(yv[2 * q], yv[2 * q + 1]);
                yna[mt][ks] = __builtin_bit_cast(bf16x8, p);
            }
        }
    };

    bf16x8 xaA[2][2], ynaA[2][2], xaB[2][2], ynaB[2][2];
    prologue(xgA, xaA, ynaA);
    prologue(xgB, xaB, ynaB);

    f32x4 accA[2][4], accB[2][4];
    #pragma unroll
    for (int mt = 0; mt < 2; mt++)
        #pragma unroll
        for (int nt = 0; nt < 4; nt++) {
            accA[mt][nt] = (f32x4){0.f, 0.f, 0.f, 0.f};
            accB[mt][nt] = (f32x4){0.f, 0.f, 0.f, 0.f};
        }

    const f32x4 z4 = {0.f, 0.f, 0.f, 0.f};
    const bf16x8 z8 = {0, 0, 0, 0, 0, 0, 0, 0};
    const f32x16 z16 = {0.f,0.f,0.f,0.f,0.f,0.f,0.f,0.f,0.f,0.f,0.f,0.f,0.f,0.f,0.f,0.f};

    // FWT swizzle constants (16B block ^= (l15>>2)&3)
    const int sw4 = (l15 >> 2) & 3;
    unsigned char* w0p = fwb + ((((quad >> 1) ^ sw4)) << 4) + (quad & 1) * 8;
    unsigned char* w1p = fwb + (((((quad >> 1) ^ sw4)) ^ 2) << 4) + (quad & 1) * 8;
    unsigned char* brp = fwb + l15 * 64 + ((quad ^ sw4) << 4);

    const int uc = (r32 < 25) ? r32 : 24;   // clamped topo row

    // in-register softmax + P store (r5 layout, verified). dd: lane r32 = row u;
    // v(r) = (r&3)+8*(r>>2)+4*hi.
    auto softmax_store = [&](f32x16& dd, const float* tp, unsigned char* Pb) {
        dd[12] = hi ? -3e30f : dd[12];
        dd[13] = -3e30f; dd[14] = -3e30f; dd[15] = -3e30f;
        float t8[8];
        #pragma unroll
        for (int r = 0; r < 8; r++) t8[r] = fmaxf(dd[r], dd[r + 8]);
        #pragma unroll
        for (int r = 0; r < 4; r++) t8[r] = fmaxf(t8[r], t8[r + 4]);
        float m = fmaxf(fmaxf(t8[0], t8[1]), fmaxf(t8[2], t8[3]));
        m = fmaxf(m, __shfl_xor(m, 32));
        float s0 = 0.f, s1 = 0.f, s2 = 0.f, s3 = 0.f;
        #pragma unroll
        for (int r = 0; r < 16; r += 4) {
            dd[r]     = __builtin_amdgcn_exp2f(dd[r] - m);     s0 += dd[r];
            dd[r + 1] = __builtin_amdgcn_exp2f(dd[r + 1] - m); s1 += dd[r + 1];
            dd[r + 2] = __builtin_amdgcn_exp2f(dd[r + 2] - m); s2 += dd[r + 2];
            dd[r + 3] = __builtin_amdgcn_exp2f(dd[r + 3] - m); s3 += dd[r + 3];
        }
        float s = (s0 + s1) + (s2 + s3);
        s += __shfl_xor(s, 32);
        float inv = __builtin_amdgcn_rcpf(s);
        #pragma unroll
        for (int r = 0; r < 16; r++) dd[r] = dd[r] * inv * tp[r];
        if (r32 < 25) {
            unsigned char* rowp = Pb + r32 * 80 + hi * 8;
            *(i32x2*)(rowp +  0) = (i32x2){pack2(dd[0], dd[1]),   pack2(dd[2], dd[3])};
            *(i32x2*)(rowp + 16) = (i32x2){pack2(dd[4], dd[5]),   pack2(dd[6], dd[7])};
            *(i32x2*)(rowp + 32) = (i32x2){pack2(dd[8], dd[9]),   pack2(dd[10], dd[11])};
            *(i32x2*)(rowp + 48) = (i32x2){pack2(dd[12], dd[13]), pack2(dd[14], dd[15])};
        }
    };

    auto topo_gather = [&](int h, float (&tp)[16]) {
        const float* tb = topo + h * 625 + uc * 25 + hi * 4;
        #pragma unroll
        for (int r = 0; r < 16; r++) {
            int off = (r < 12) ? ((r & 3) + (r >> 2) * 8)
                    : (r == 12 ? (hi ? 0 : 24) : 0);   // pad offsets clamped in-bounds
            tp[r] = tb[off];
        }
    };

    // dots (swapped: A=K, B=Q) for one tile/hh; tile offset td*9216 via imm
    auto dots = [&](int tdoff, int hh) -> f32x16 {
        bf16x8 ak = z8, bq = z8;
        if (hi == 0) {
            ak = *(const bf16x8*)((unsigned char*)kbuf + tdoff + r32 * 48 + hh * 16);
            bq = *(const bf16x8*)((unsigned char*)qbuf + tdoff + r32 * 48 + hh * 16);
        }
        return __builtin_amdgcn_mfma_f32_32x32x16_bf16(ak, bq, z16, 0, 0, 0);
    };

    auto fw_phase = [&](bf16x8 (&xa)[2][2], const bf16x8* w2, int tdoff) {
        #pragma unroll
        for (int nt = 0; nt < 4; nt++) {
            f32x4 dw0 = MFMA16(xa[0][0], w2[2 * nt], z4);
            dw0 = MFMA16(xa[0][1], w2[2 * nt + 1], dw0);
            f32x4 dw1 = MFMA16(xa[1][0], w2[2 * nt], z4);
            dw1 = MFMA16(xa[1][1], w2[2 * nt + 1], dw1);
            i32x2 q0 = {pack2(dw0[0], dw0[1]), pack2(dw0[2], dw0[3])};
            i32x2 q1 = {pack2(dw1[0], dw1[1]), pack2(dw1[2], dw1[3])};
            *(i32x2*)(w0p + tdoff + nt * 1024 + l15 * 64) = q0;
            *(i32x2*)(w1p + tdoff + nt * 1024 + l15 * 64) = q1;
        }
    };

    auto pv_phase = [&](f32x4 (&acc)[2][4], unsigned char* Pb, int tdoff) {
        bf16x8 ag0 = *(const bf16x8*)(Pb + tdoff + l15 * 80 + quad * 16);
        bf16x8 ag1 = *(const bf16x8*)(Pb + tdoff + 1280 + l15 * 80 + quad * 16);
        #pragma unroll
        for (int nt = 0; nt < 4; nt++) {
            bf16x8 br = *(const bf16x8*)(brp + tdoff + nt * 1024);
            acc[0][nt] = MFMA16(ag0, br, acc[0][nt]);
            acc[1][nt] = MFMA16(ag1, br, acc[1][nt]);
        }
    };

    // ---- head-pair loop (runtime hp; all LDS addressing hp-invariant) ----
    for (int hp = 0; hp < 4; hp++) {
        // qk: weights shared across tiles
        #pragma unroll
        for (int tsel = 0; tsel < 2; tsel++) {
            int nt = tsel ? (4 + hp) : hp;
            bf16x8 b0 = *(const bf16x8*)&wqk[(nt * 2 + 0) * 512 + lane * 8];
            bf16x8 b1 = *(const bf16x8*)&wqk[(nt * 2 + 1) * 512 + lane * 8];
            float bias = b_qk[(tsel ? 64 : 0) + hp * 16 + l15];
            #pragma unroll
            for (int td = 0; td < 2; td++) {
                unsigned short* buf = (unsigned short*)((unsigned char*)(tsel ? kbuf : qbuf) + td * 9216);
                #pragma unroll
                for (int mt = 0; mt < 2; mt++) {
                    const bf16x8* yn = td ? ynaB[mt] : ynaA[mt];
                    f32x4 d = MFMA16(yn[0], b0, z4);
                    d = MFMA16(yn[1], b1, d);
                    #pragma unroll
                    for (int r = 0; r < 4; r++) {
                        int u = mt * 16 + quad * 4 + r;
                        if (u < 25) {
                            float val = d[r] + bias;
                            if (!tsel) val *= SCALE_L2E;
                            buf[u * 24 + l15] = bfh(val);
                        }
                    }
                }
            }
        }

        float tp0[16];
        topo_gather(hp * 2, tp0);          // shared by both tiles
        LGKM0();                           // q/k (A and B) visible

        // dots+softmax hh=0, tiles interleaved (independent chains)
        {
            f32x16 pA = dots(0, 0);
            f32x16 pB = dots(9216, 0);
            softmax_store(pA, tp0, pb0);
            softmax_store(pB, tp0, pb0 + 9216);
        }
        float tp1[16];
        topo_gather(hp * 2 + 1, tp1);
        // dots+softmax hh=1
        {
            f32x16 pA = dots(0, 1);
            f32x16 pB = dots(9216, 1);
            softmax_store(pA, tp1, pb1);
            softmax_store(pB, tp1, pb1 + 9216);
        }

        // W2^T frags hh=0 (shared); FW both tiles (overlays q/k after dots reads)
        bf16x8 w2e[8];
        #pragma unroll
        for (int nt = 0; nt < 4; nt++) {
            int h = hp * 2;
            w2e[2 * nt]     = *(const bf16x8*)&w2f[((h * 4 + nt) * 2 + 0) * 512 + lane * 8];
            w2e[2 * nt + 1] = *(const bf16x8*)&w2f[((h * 4 + nt) * 2 + 1) * 512 + lane * 8];
        }
        fw_phase(xaA, w2e, 0);
        fw_phase(xaB, w2e, 9216);
        // W2^T frags hh=1 issued now (vmcnt; hide under wait + PV0)
        bf16x8 w2o[8];
        #pragma unroll
        for (int nt = 0; nt < 4; nt++) {
            int h = hp * 2 + 1;
            w2o[2 * nt]     = *(const bf16x8*)&w2f[((h * 4 + nt) * 2 + 0) * 512 + lane * 8];
            w2o[2 * nt + 1] = *(const bf16x8*)&w2f[((h * 4 + nt) * 2 + 1) * 512 + lane * 8];
        }
        LGKM0();   // P + FWT(hh=0) both tiles visible

        pv_phase(accA, pb0, 0);
        pv_phase(accB, pb0, 9216);

        fw_phase(xaA, w2o, 0);    // after PV0 reads (same-wave DS order)
        fw_phase(xaB, w2o, 9216);
        LGKM0();   // FWT(hh=1) visible

        pv_phase(accA, pb1, 0);
        pv_phase(accB, pb1, 9216);
    }

    // ---- epilogue: BN + residual + ReLU, both tiles ----
    auto epilogue = [&](f32x4 (&acc)[2][4], const float* xg, float* og) {
        #pragma unroll
        for (int nt = 0; nt < 4; nt++) {
            int o = nt * 16 + l15;
            float gA = bnA[o], gB = bnB[o];
            #pragma unroll
            for (int mt = 0; mt < 2; mt++) {
                int ub = mt * 16 + quad * 4;
                #pragma unroll
                for (int r = 0; r < 4; r++) {
                    int u = ub + r;
                    if (u < 25) {
                        float val = acc[mt][nt][r] * gA + gB + xg[o * 6400 + u];
                        og[o * 6400 + u] = fmaxf(val, 0.f);
                    }
                }
            }
        }
    };
    epilogue(accA, xgA, ogA);
    epilogue(accB, xgB, ogB);
}

extern "C" void kernel_launch(void* const* d_in, const int* in_sizes, int n_in,
                              void* d_out, int out_size, void* d_ws, size_t ws_size,
                              hipStream_t stream) {
    const float* x      = (const float*)d_in[0];
    const float* ln_g   = (const float*)d_in[1];
    const float* ln_b   = (const float*)d_in[2];
    const float* w_qk   = (const float*)d_in[3];
    const float* b_qk   = (const float*)d_in[4];
    const float* topo   = (const float*)d_in[5];
    const float* conv_w = (const float*)d_in[6];
    const float* conv_b = (const float*)d_in[7];
    const float* bn_g   = (const float*)d_in[8];
    const float* bn_b   = (const float*)d_in[9];
    const float* bn_m   = (const float*)d_in[10];
    const float* bn_v   = (const float*)d_in[11];
    float* outp = (float*)d_out;
    unsigned short* wsp = (unsigned short*)d_ws;

    hipLaunchKernelGGL(prep_kernel, dim3(161), dim3(256), 0, stream,
                       w_qk, conv_w, conv_b, bn_g, bn_b, bn_m, bn_v, wsp);
    hipLaunchKernelGGL(sagc_kernel, dim3(1024), dim3(256), 0, stream,
                       x, ln_g, ln_b, b_qk, topo, (const unsigned short*)wsp, outp);
}

// Round 7
// 193.499 us; speedup vs baseline: 1.1392x; 1.1392x over previous
//
#include <hip/hip_runtime.h>
#include <math.h>

#define SCALE_L2E 0.51006972157f   // (1/sqrt(8)) * log2(e) -- softmax done in exp2 domain
#define EPSV 1e-5f

typedef __attribute__((ext_vector_type(8))) short bf16x8;
typedef __attribute__((ext_vector_type(4))) float f32x4;
typedef __attribute__((ext_vector_type(16))) float f32x16;
typedef __attribute__((ext_vector_type(4))) int i32x4;
typedef __attribute__((ext_vector_type(2))) int i32x2;

static __device__ __forceinline__ unsigned short bfh(float f) {
    return (unsigned short)(__builtin_bit_cast(unsigned int, f) >> 16);
}
static __device__ __forceinline__ int pack2(float lo, float hi) {
    return __builtin_amdgcn_perm(__builtin_bit_cast(unsigned int, hi),
                                 __builtin_bit_cast(unsigned int, lo), 0x07060302u);
}
#define LGKM0() __asm__ __volatile__("s_waitcnt lgkmcnt(0)" ::: "memory")
#define MFMA16(a, b, c) __builtin_amdgcn_mfma_f32_16x16x32_bf16((a), (b), (c), 0, 0, 0)

// ws layout: [0,8192) ushort wqk B-frags; [8192,40960) ushort W2ᵀ B-frags;
//            byte 81920: float bnA[64], bnB[64]
__global__ void prep_kernel(const float* __restrict__ w_qk,
                            const float* __restrict__ conv_w,
                            const float* __restrict__ conv_b,
                            const float* __restrict__ bn_g, const float* __restrict__ bn_b,
                            const float* __restrict__ bn_m, const float* __restrict__ bn_v,
                            unsigned short* __restrict__ ws) {
    int i = blockIdx.x * 256 + threadIdx.x;
    if (i < 8192) {
        int f = i >> 9, rem = i & 511, l = rem >> 3, j = rem & 7;
        int nt = f >> 1, ks = f & 1;
        int k = ks * 32 + (l >> 4) * 8 + j;
        int nn = nt * 16 + (l & 15);
        ws[i] = bfh(w_qk[k * 128 + nn]);
    } else if (i < 40960) {
        int i2 = i - 8192;
        int g = i2 >> 9, rem = i2 & 511, l = rem >> 3, j = rem & 7;
        int h = g >> 3, nt = (g >> 1) & 3, ks = g & 1;
        int c = ks * 32 + (l >> 4) * 8 + j;
        int o = nt * 16 + (l & 15);
        ws[i] = bfh(conv_w[h * 4096 + o * 64 + c]);
    } else if (i < 41024) {
        int o = i - 40960;
        float gv = bn_g[o] * rsqrtf(bn_v[o] + EPSV);
        float bb = bn_b[o] - bn_m[o] * gv;
        float cb = 0.f;
        for (int h = 0; h < 8; h++) cb += conv_b[h * 64 + o];
        float* wsf = (float*)(ws + 40960);
        wsf[o] = gv;
        wsf[64 + o] = bb + cb * gv;
    }
}

// R7: COOPERATIVE HEAD-SPLIT. One block = one (n,t) tile; each of the 4 waves
// runs exactly ONE head-pair (the verified r5 hp-body with hp = wv), then a
// block-wide LDS reduction over the 4 partial accs + BN/residual/ReLU epilogue.
// Rationale (MEASURED r0-r6): dur pinned ~98us across occupancy 20-40%, wait
// counts, swizzles => per-wave serial chain is the limiter. r6 (2 tiles/wave,
// fatter wave) REGRESSED to 130us (spill: WRITE 54->76MB; occ 11%). This goes
// the opposite way: chain per wave = prologue + 1 hp + reduce (~3-4x shorter),
// register pressure LOWER than r5 (yna dies after the single qk phase).
// LDS: 4 x 9216 B wave-private regions (r5 layout), aliased after syncthreads
// by the reduction buffer red[w][o][u]: 4 x 64o x 36u floats = 36864 B total.
//   wave-private: qbuf[32][24]u16 @0, kbuf @1536 (then FWT swizzled overlay),
//                 P0 [32][40]u16 @4096, P1 @6656.
// Grid 8192 blocks (1 tile each). 36864 B -> 4 blocks/CU; VGPR ~90-110 -> ok.
// Spill tripwire (MEASURED r1/r2/r6): FETCH > 70 MB => revert.
__global__ __launch_bounds__(256, 2)
void sagc_kernel(const float* __restrict__ x,
                 const float* __restrict__ ln_g, const float* __restrict__ ln_b,
                 const float* __restrict__ b_qk,
                 const float* __restrict__ topo,
                 const unsigned short* __restrict__ ws,
                 float* __restrict__ out)
{
    __shared__ __align__(16) unsigned char smem[36864];
    const int tid = threadIdx.x;
    const int lane = tid & 63, wv = tid >> 6;
    const int l15 = lane & 15, quad = lane >> 4;
    const int r32 = lane & 31, hi = lane >> 5;

    unsigned char* my = smem + wv * 9216;
    unsigned short* qbuf = (unsigned short*)my;            // [32][24] u16
    unsigned short* kbuf = (unsigned short*)(my + 1536);
    unsigned char*  fwb  = my;                             // FWT swizzled (overlays q/k)
    unsigned char*  pb0  = my + 4096;                      // P0 [32][40] u16
    unsigned char*  pb1  = my + 6656;                      // P1

    const unsigned short* wqk = ws;
    const unsigned short* w2f = ws + 8192;
    const float* bnA = (const float*)(ws + 40960);
    const float* bnB = bnA + 64;

    const int tile = blockIdx.x;                           // one tile per block
    const int n = tile >> 8, t = tile & 255;
    const float* xg = x + (size_t)n * 409600 + (size_t)t * 25;   // + c*6400 + v
    float* og = out + (size_t)n * 409600 + (size_t)t * 25;

    const int hp = wv;                                     // this wave's head-pair

    // ---- prologue (redundant per wave; same addresses -> L1-hot) ----
    float xf[2][2][8];
    #pragma unroll
    for (int mt = 0; mt < 2; mt++) {
        const int v = mt * 16 + l15;
        const bool ok = (v < 25);
        const float* xc = xg + v;
        #pragma unroll
        for (int ks = 0; ks < 2; ks++)
            #pragma unroll
            for (int j = 0; j < 8; j++) {
                int c = ks * 32 + quad * 8 + j;
                xf[mt][ks][j] = ok ? xc[c * 6400] : 0.f;
            }
    }
    bf16x8 xa[2][2];
    float sum_[2] = {0.f, 0.f}, ssq_[2] = {0.f, 0.f};
    #pragma unroll
    for (int mt = 0; mt < 2; mt++)
        #pragma unroll
        for (int ks = 0; ks < 2; ks++) {
            i32x4 pa;
            #pragma unroll
            for (int q = 0; q < 4; q++)
                pa[q] = pack2(xf[mt][ks][2 * q], xf[mt][ks][2 * q + 1]);
            xa[mt][ks] = __builtin_bit_cast(bf16x8, pa);
            #pragma unroll
            for (int j = 0; j < 8; j++) {
                float a = xf[mt][ks][j];
                sum_[mt] += a;
                ssq_[mt] += a * a;
            }
        }
    float muv[2], rsv[2];
    #pragma unroll
    for (int mt = 0; mt < 2; mt++) {
        sum_[mt] += __shfl_xor(sum_[mt], 16);
        sum_[mt] += __shfl_xor(sum_[mt], 32);
        ssq_[mt] += __shfl_xor(ssq_[mt], 16);
        ssq_[mt] += __shfl_xor(ssq_[mt], 32);
        muv[mt] = sum_[mt] * 0.015625f;
        rsv[mt] = rsqrtf(ssq_[mt] * 0.015625f - muv[mt] * muv[mt] + EPSV);
    }
    bf16x8 yna[2][2];
    #pragma unroll
    for (int ks = 0; ks < 2; ks++) {
        f32x4 ga = *(const f32x4*)&ln_g[ks * 32 + quad * 8];
        f32x4 gb = *(const f32x4*)&ln_g[ks * 32 + quad * 8 + 4];
        f32x4 ba = *(const f32x4*)&ln_b[ks * 32 + quad * 8];
        f32x4 bb = *(const f32x4*)&ln_b[ks * 32 + quad * 8 + 4];
        #pragma unroll
        for (int mt = 0; mt < 2; mt++) {
            float yv[8];
            #pragma unroll
            for (int j = 0; j < 8; j++) {
                float g = (j < 4) ? ga[j] : gb[j - 4];
                float bt = (j < 4) ? ba[j] : bb[j - 4];
                yv[j] = (xf[mt][ks][j] - muv[mt]) * rsv[mt] * g + bt;
            }
            i32x4 p;
            #pragma unroll
            for (int q = 0; q < 4; q++) p[q] = pack2(yv[2 * q], yv[2 * q + 1]);
            yna[mt][ks] = __builtin_bit_cast(bf16x8, p);
        }
    }

    f32x4 acc[2][4];
    #pragma unroll
    for (int mt = 0; mt < 2; mt++)
        #pragma unroll
        for (int nt = 0; nt < 4; nt++)
            acc[mt][nt] = (f32x4){0.f, 0.f, 0.f, 0.f};

    const f32x4 z4 = {0.f, 0.f, 0.f, 0.f};
    const bf16x8 z8 = {0, 0, 0, 0, 0, 0, 0, 0};
    const f32x16 z16 = {0.f,0.f,0.f,0.f,0.f,0.f,0.f,0.f,0.f,0.f,0.f,0.f,0.f,0.f,0.f,0.f};

    // FWT swizzle constants (16B block ^= (l15>>2)&3)
    const int sw4 = (l15 >> 2) & 3;
    unsigned char* w0p = fwb + ((((quad >> 1) ^ sw4)) << 4) + (quad & 1) * 8;
    unsigned char* w1p = fwb + (((((quad >> 1) ^ sw4)) ^ 2) << 4) + (quad & 1) * 8;
    unsigned char* brp = fwb + l15 * 64 + ((quad ^ sw4) << 4);

    const int uc = (r32 < 25) ? r32 : 24;   // clamped topo row

    // in-register softmax + P store (r5 layout, verified). dd: lane r32 = row u;
    // v(r) = (r&3)+8*(r>>2)+4*hi.
    auto softmax_store = [&](f32x16& dd, const float* tp, unsigned char* Pb) {
        dd[12] = hi ? -3e30f : dd[12];
        dd[13] = -3e30f; dd[14] = -3e30f; dd[15] = -3e30f;
        float t8[8];
        #pragma unroll
        for (int r = 0; r < 8; r++) t8[r] = fmaxf(dd[r], dd[r + 8]);
        #pragma unroll
        for (int r = 0; r < 4; r++) t8[r] = fmaxf(t8[r], t8[r + 4]);
        float m = fmaxf(fmaxf(t8[0], t8[1]), fmaxf(t8[2], t8[3]));
        m = fmaxf(m, __shfl_xor(m, 32));
        float s0 = 0.f, s1 = 0.f, s2 = 0.f, s3 = 0.f;
        #pragma unroll
        for (int r = 0; r < 16; r += 4) {
            dd[r]     = __builtin_amdgcn_exp2f(dd[r] - m);     s0 += dd[r];
            dd[r + 1] = __builtin_amdgcn_exp2f(dd[r + 1] - m); s1 += dd[r + 1];
            dd[r + 2] = __builtin_amdgcn_exp2f(dd[r + 2] - m); s2 += dd[r + 2];
            dd[r + 3] = __builtin_amdgcn_exp2f(dd[r + 3] - m); s3 += dd[r + 3];
        }
        float s = (s0 + s1) + (s2 + s3);
        s += __shfl_xor(s, 32);
        float inv = __builtin_amdgcn_rcpf(s);
        #pragma unroll
        for (int r = 0; r < 16; r++) dd[r] = dd[r] * inv * tp[r];
        if (r32 < 25) {
            unsigned char* rowp = Pb + r32 * 80 + hi * 8;
            *(i32x2*)(rowp +  0) = (i32x2){pack2(dd[0], dd[1]),   pack2(dd[2], dd[3])};
            *(i32x2*)(rowp + 16) = (i32x2){pack2(dd[4], dd[5]),   pack2(dd[6], dd[7])};
            *(i32x2*)(rowp + 32) = (i32x2){pack2(dd[8], dd[9]),   pack2(dd[10], dd[11])};
            *(i32x2*)(rowp + 48) = (i32x2){pack2(dd[12], dd[13]), pack2(dd[14], dd[15])};
        }
    };

    auto topo_gather = [&](int h, float (&tp)[16]) {
        const float* tb = topo + h * 625 + uc * 25 + hi * 4;
        #pragma unroll
        for (int r = 0; r < 16; r++) {
            int off = (r < 12) ? ((r & 3) + (r >> 2) * 8)
                    : (r == 12 ? (hi ? 0 : 24) : 0);   // pad offsets clamped in-bounds
            tp[r] = tb[off];
        }
    };

    // ---- this wave's single head-pair (exact r5 phase body, hp = wv) ----
    // qk: q-tile nt=hp (SCALE*log2e folded), k-tile nt=4+hp
    #pragma unroll
    for (int tsel = 0; tsel < 2; tsel++) {
        int nt = tsel ? (4 + hp) : hp;
        bf16x8 b0 = *(const bf16x8*)&wqk[(nt * 2 + 0) * 512 + lane * 8];
        bf16x8 b1 = *(const bf16x8*)&wqk[(nt * 2 + 1) * 512 + lane * 8];
        float bias = b_qk[(tsel ? 64 : 0) + hp * 16 + l15];
        unsigned short* buf = tsel ? kbuf : qbuf;
        #pragma unroll
        for (int mt = 0; mt < 2; mt++) {
            f32x4 d = MFMA16(yna[mt][0], b0, z4);
            d = MFMA16(yna[mt][1], b1, d);
            #pragma unroll
            for (int r = 0; r < 4; r++) {
                int u = mt * 16 + quad * 4 + r;
                if (u < 25) {
                    float val = d[r] + bias;
                    if (!tsel) val *= SCALE_L2E;
                    buf[u * 24 + l15] = bfh(val);
                }
            }
        }
    }

    float tp0[16];
    topo_gather(hp * 2, tp0);
    LGKM0();   // q/k visible

    // dots (swapped: A=K, B=Q) hh=0/1, softmax in-register
    f32x16 p0, p1;
    {
        bf16x8 ak = z8, bq = z8;
        if (hi == 0) {
            ak = *(const bf16x8*)&kbuf[r32 * 24 + 0];
            bq = *(const bf16x8*)&qbuf[r32 * 24 + 0];
        }
        p0 = __builtin_amdgcn_mfma_f32_32x32x16_bf16(ak, bq, z16, 0, 0, 0);
    }
    float tp1[16];
    topo_gather(hp * 2 + 1, tp1);
    {
        bf16x8 ak = z8, bq = z8;
        if (hi == 0) {
            ak = *(const bf16x8*)&kbuf[r32 * 24 + 8];
            bq = *(const bf16x8*)&qbuf[r32 * 24 + 8];
        }
        p1 = __builtin_amdgcn_mfma_f32_32x32x16_bf16(ak, bq, z16, 0, 0, 0);
    }
    softmax_store(p0, tp0, pb0);
    softmax_store(p1, tp1, pb1);

    // FW hh=0 (overlays q/k after dots reads; same-wave DS ordering)
    bf16x8 w2e[8];
    #pragma unroll
    for (int nt = 0; nt < 4; nt++) {
        int h = hp * 2;
        w2e[2 * nt]     = *(const bf16x8*)&w2f[((h * 4 + nt) * 2 + 0) * 512 + lane * 8];
        w2e[2 * nt + 1] = *(const bf16x8*)&w2f[((h * 4 + nt) * 2 + 1) * 512 + lane * 8];
    }
    #pragma unroll
    for (int nt = 0; nt < 4; nt++) {
        f32x4 dw0 = MFMA16(xa[0][0], w2e[2 * nt], z4);
        dw0 = MFMA16(xa[0][1], w2e[2 * nt + 1], dw0);
        f32x4 dw1 = MFMA16(xa[1][0], w2e[2 * nt], z4);
        dw1 = MFMA16(xa[1][1], w2e[2 * nt + 1], dw1);
        i32x2 q0 = {pack2(dw0[0], dw0[1]), pack2(dw0[2], dw0[3])};
        i32x2 q1 = {pack2(dw1[0], dw1[1]), pack2(dw1[2], dw1[3])};
        *(i32x2*)(w0p + nt * 1024 + l15 * 64) = q0;
        *(i32x2*)(w1p + nt * 1024 + l15 * 64) = q1;
    }
    bf16x8 w2o[8];
    #pragma unroll
    for (int nt = 0; nt < 4; nt++) {
        int h = hp * 2 + 1;
        w2o[2 * nt]     = *(const bf16x8*)&w2f[((h * 4 + nt) * 2 + 0) * 512 + lane * 8];
        w2o[2 * nt + 1] = *(const bf16x8*)&w2f[((h * 4 + nt) * 2 + 1) * 512 + lane * 8];
    }
    LGKM0();   // P0/P1 + FWT(hh=0) visible

    // PV hh=0
    {
        bf16x8 ag0 = *(const bf16x8*)(pb0 + l15 * 80 + quad * 16);
        bf16x8 ag1 = *(const bf16x8*)(pb0 + 1280 + l15 * 80 + quad * 16);
        #pragma unroll
        for (int nt = 0; nt < 4; nt++) {
            bf16x8 br = *(const bf16x8*)(brp + nt * 1024);
            acc[0][nt] = MFMA16(ag0, br, acc[0][nt]);
            acc[1][nt] = MFMA16(ag1, br, acc[1][nt]);
        }
    }

    // FW hh=1 -> FWT (after PV0 reads)
    #pragma unroll
    for (int nt = 0; nt < 4; nt++) {
        f32x4 dw0 = MFMA16(xa[0][0], w2o[2 * nt], z4);
        dw0 = MFMA16(xa[0][1], w2o[2 * nt + 1], dw0);
        f32x4 dw1 = MFMA16(xa[1][0], w2o[2 * nt], z4);
        dw1 = MFMA16(xa[1][1], w2o[2 * nt + 1], dw1);
        i32x2 q0 = {pack2(dw0[0], dw0[1]), pack2(dw0[2], dw0[3])};
        i32x2 q1 = {pack2(dw1[0], dw1[1]), pack2(dw1[2], dw1[3])};
        *(i32x2*)(w0p + nt * 1024 + l15 * 64) = q0;
        *(i32x2*)(w1p + nt * 1024 + l15 * 64) = q1;
    }
    LGKM0();   // FWT(hh=1) visible

    // PV hh=1
    {
        bf16x8 ag0 = *(const bf16x8*)(pb1 + l15 * 80 + quad * 16);
        bf16x8 ag1 = *(const bf16x8*)(pb1 + 1280 + l15 * 80 + quad * 16);
        #pragma unroll
        for (int nt = 0; nt < 4; nt++) {
            bf16x8 br = *(const bf16x8*)(brp + nt * 1024);
            acc[0][nt] = MFMA16(ag0, br, acc[0][nt]);
            acc[1][nt] = MFMA16(ag1, br, acc[1][nt]);
        }
    }

    // ---- cross-wave reduction: red[w][o][u] = 4 x 64 x 36 floats (36864 B) ----
    __syncthreads();                       // all wave-private LDS use done
    {
        float* red = (float*)smem + wv * 2304;
        #pragma unroll
        for (int mt = 0; mt < 2; mt++)
            #pragma unroll
            for (int nt = 0; nt < 4; nt++)
                *(f32x4*)&red[(nt * 16 + l15) * 36 + mt * 16 + quad * 4] = acc[mt][nt];
    }
    __syncthreads();

    // ---- epilogue: wave wv handles o in [wv*16, wv*16+16) ----
    {
        const float* redf = (const float*)smem;
        const int o = wv * 16 + l15;
        const float gA = bnA[o], gB = bnB[o];
        const float* xo = xg + (size_t)o * 6400;
        float* oo = og + (size_t)o * 6400;
        #pragma unroll
        for (int mt = 0; mt < 2; mt++) {
            const int ub = mt * 16 + quad * 4;
            f32x4 s = {0.f, 0.f, 0.f, 0.f};
            #pragma unroll
            for (int w = 0; w < 4; w++)
                s += *(const f32x4*)&redf[w * 2304 + o * 36 + ub];
            if (ub + 3 < 25) {
                f32x4 xr = *(const f32x4*)&xo[ub];
                f32x4 v;
                #pragma unroll
                for (int r = 0; r < 4; r++) v[r] = fmaxf(s[r] * gA + gB + xr[r], 0.f);
                *(f32x4*)&oo[ub] = v;
            } else if (ub < 25) {   // ub == 24
                oo[ub] = fmaxf(s[0] * gA + gB + xo[ub], 0.f);
            }
        }
    }
}

extern "C" void kernel_launch(void* const* d_in, const int* in_sizes, int n_in,
                              void* d_out, int out_size, void* d_ws, size_t ws_size,
                              hipStream_t stream) {
    const float* x      = (const float*)d_in[0];
    const float* ln_g   = (const float*)d_in[1];
    const float* ln_b   = (const float*)d_in[2];
    const float* w_qk   = (const float*)d_in[3];
    const float* b_qk   = (const float*)d_in[4];
    const float* topo   = (const float*)d_in[5];
    const float* conv_w = (const float*)d_in[6];
    const float* conv_b = (const float*)d_in[7];
    const float* bn_g   = (const float*)d_in[8];
    const float* bn_b   = (const float*)d_in[9];
    const float* bn_m   = (const float*)d_in[10];
    const float* bn_v   = (const float*)d_in[11];
    float* outp = (float*)d_out;
    unsigned short* wsp = (unsigned short*)d_ws;

    hipLaunchKernelGGL(prep_kernel, dim3(161), dim3(256), 0, stream,
                       w_qk, conv_w, conv_b, bn_g, bn_b, bn_m, bn_v, wsp);
    hipLaunchKernelGGL(sagc_kernel, dim3(8192), dim3(256), 0, stream,
                       x, ln_g, ln_b, b_qk, topo, (const unsigned short*)wsp, outp);
}

// Round 8
// 188.839 us; speedup vs baseline: 1.1673x; 1.0247x over previous
//
#include <hip/hip_runtime.h>
#include <math.h>

#define SCALE_L2E 0.51006972157f   // (1/sqrt(8)) * log2(e) -- softmax done in exp2 domain
#define EPSV 1e-5f

typedef __attribute__((ext_vector_type(8))) short bf16x8;
typedef __attribute__((ext_vector_type(4))) float f32x4;
typedef __attribute__((ext_vector_type(16))) float f32x16;
typedef __attribute__((ext_vector_type(4))) int i32x4;
typedef __attribute__((ext_vector_type(2))) int i32x2;

static __device__ __forceinline__ unsigned short bfh(float f) {
    return (unsigned short)(__builtin_bit_cast(unsigned int, f) >> 16);
}
static __device__ __forceinline__ int pack2(float lo, float hi) {
    return __builtin_amdgcn_perm(__builtin_bit_cast(unsigned int, hi),
                                 __builtin_bit_cast(unsigned int, lo), 0x07060302u);
}
#define LGKM0() __asm__ __volatile__("s_waitcnt lgkmcnt(0)" ::: "memory")
#define MFMA16(a, b, c) __builtin_amdgcn_mfma_f32_16x16x32_bf16((a), (b), (c), 0, 0, 0)

// ws layout: [0,8192) ushort wqk B-frags; [8192,40960) ushort W2ᵀ B-frags;
//            byte 81920: float bnA[64], bnB[64]
__global__ void prep_kernel(const float* __restrict__ w_qk,
                            const float* __restrict__ conv_w,
                            const float* __restrict__ conv_b,
                            const float* __restrict__ bn_g, const float* __restrict__ bn_b,
                            const float* __restrict__ bn_m, const float* __restrict__ bn_v,
                            unsigned short* __restrict__ ws) {
    int i = blockIdx.x * 256 + threadIdx.x;
    if (i < 8192) {
        int f = i >> 9, rem = i & 511, l = rem >> 3, j = rem & 7;
        int nt = f >> 1, ks = f & 1;
        int k = ks * 32 + (l >> 4) * 8 + j;
        int nn = nt * 16 + (l & 15);
        ws[i] = bfh(w_qk[k * 128 + nn]);
    } else if (i < 40960) {
        int i2 = i - 8192;
        int g = i2 >> 9, rem = i2 & 511, l = rem >> 3, j = rem & 7;
        int h = g >> 3, nt = (g >> 1) & 3, ks = g & 1;
        int c = ks * 32 + (l >> 4) * 8 + j;
        int o = nt * 16 + (l & 15);
        ws[i] = bfh(conv_w[h * 4096 + o * 64 + c]);
    } else if (i < 41024) {
        int o = i - 40960;
        float gv = bn_g[o] * rsqrtf(bn_v[o] + EPSV);
        float bb = bn_b[o] - bn_m[o] * gv;
        float cb = 0.f;
        for (int h = 0; h < 8; h++) cb += conv_b[h * 64 + o];
        float* wsf = (float*)(ws + 40960);
        wsf[o] = gv;
        wsf[64 + o] = bb + cb * gv;
    }
}

// R8: r7 (cooperative head-split: block = tile, wave = head-pair, LDS reduce)
// + COOPERATIVE PROLOGUE. r7 post-mortem (MEASURED): chain 4x shorter, occ 38%,
// VALUBusy 28->46%, dur UNCHANGED ~100us; FETCH 57->82MB from the 4x-redundant
// per-wave prologue (each wave re-loaded + re-LN'd the whole x tile). => closest
// binding resource is VALU/issue work, and the removable work is the prologue.
// Here the prologue runs ONCE per block, row-split across waves (wave wv: rows
// [8wv,8wv+8), lane rl*8+cp: 8 contiguous channels; LN reduce = 3 shfl_xor in
// the 8-lane row group), staged to shared LDS xbS/ynS [32 rows][128B] bf16 with
// a 16B-block XOR swizzle (blk ^= row&7 -> frag reads are <=2-way banked).
// Every wave then reads its xa/yna frags (8x ds_read_b128) and runs the r7 body.
// Shared 8KB region [4096,12288) aliases wave0 P-bufs + wave1 q/k bufs: safe,
// frag reads complete before the 2nd __syncthreads, after which region is dead.
// LDS total unchanged 36864 B -> 4 blocks/CU.
// Spill tripwire (MEASURED r1/r2/r6): FETCH > 70 MB => revert.
__global__ __launch_bounds__(256, 2)
void sagc_kernel(const float* __restrict__ x,
                 const float* __restrict__ ln_g, const float* __restrict__ ln_b,
                 const float* __restrict__ b_qk,
                 const float* __restrict__ topo,
                 const unsigned short* __restrict__ ws,
                 float* __restrict__ out)
{
    __shared__ __align__(16) unsigned char smem[36864];
    const int tid = threadIdx.x;
    const int lane = tid & 63, wv = tid >> 6;
    const int l15 = lane & 15, quad = lane >> 4;
    const int r32 = lane & 31, hi = lane >> 5;

    unsigned char* my = smem + wv * 9216;
    unsigned short* qbuf = (unsigned short*)my;            // [32][24] u16
    unsigned short* kbuf = (unsigned short*)(my + 1536);
    unsigned char*  fwb  = my;                             // FWT swizzled (overlays q/k)
    unsigned char*  pb0  = my + 4096;                      // P0 [32][40] u16
    unsigned char*  pb1  = my + 6656;                      // P1

    unsigned char* xbS = smem + 4096;                      // shared [32][128B] bf16 x
    unsigned char* ynS = smem + 8192;                      // shared [32][128B] bf16 yn

    const unsigned short* wqk = ws;
    const unsigned short* w2f = ws + 8192;
    const float* bnA = (const float*)(ws + 40960);
    const float* bnB = bnA + 64;

    const int tile = blockIdx.x;                           // one tile per block
    const int n = tile >> 8, t = tile & 255;
    const float* xg = x + (size_t)n * 409600 + (size_t)t * 25;   // + c*6400 + v
    float* og = out + (size_t)n * 409600 + (size_t)t * 25;

    const int hp = wv;                                     // this wave's head-pair

    // ---- cooperative prologue: wave wv handles rows v in [8wv, 8wv+8) ----
    {
        const int rl = lane >> 3, cp = lane & 7;           // row-local, channel-part
        const int v = wv * 8 + rl;
        const bool okv = (v < 25);
        float xv[8];
        const float* xc = xg + v;
        #pragma unroll
        for (int j = 0; j < 8; j++)
            xv[j] = okv ? xc[(cp * 8 + j) * 6400] : 0.f;
        float s = 0.f, ss = 0.f;
        #pragma unroll
        for (int j = 0; j < 8; j++) { s += xv[j]; ss += xv[j] * xv[j]; }
        s  += __shfl_xor(s, 1);  s += __shfl_xor(s, 2);  s += __shfl_xor(s, 4);
        ss += __shfl_xor(ss, 1); ss += __shfl_xor(ss, 2); ss += __shfl_xor(ss, 4);
        float mu = s * 0.015625f;
        float rs = rsqrtf(ss * 0.015625f - mu * mu + EPSV);
        f32x4 ga = *(const f32x4*)&ln_g[cp * 8];
        f32x4 gb = *(const f32x4*)&ln_g[cp * 8 + 4];
        f32x4 ba = *(const f32x4*)&ln_b[cp * 8];
        f32x4 bb = *(const f32x4*)&ln_b[cp * 8 + 4];
        i32x4 px, py;
        #pragma unroll
        for (int q = 0; q < 4; q++) {
            float a0 = xv[2 * q], a1 = xv[2 * q + 1];
            float g0 = (2 * q < 4) ? ga[2 * q] : gb[2 * q - 4];
            float g1 = (2 * q + 1 < 4) ? ga[2 * q + 1] : gb[2 * q - 3];
            float b0 = (2 * q < 4) ? ba[2 * q] : bb[2 * q - 4];
            float b1 = (2 * q + 1 < 4) ? ba[2 * q + 1] : bb[2 * q - 3];
            float y0 = okv ? ((a0 - mu) * rs * g0 + b0) : 0.f;
            float y1 = okv ? ((a1 - mu) * rs * g1 + b1) : 0.f;
            px[q] = pack2(a0, a1);
            py[q] = pack2(y0, y1);
        }
        const int blk = cp ^ (v & 7);
        *(i32x4*)(xbS + v * 128 + blk * 16) = px;
        *(i32x4*)(ynS + v * 128 + blk * 16) = py;
    }
    __syncthreads();

    // ---- frag reads (blk ^= row&7 swizzle; <=2-way banks) ----
    bf16x8 xa[2][2], yna[2][2];
    #pragma unroll
    for (int mt = 0; mt < 2; mt++)
        #pragma unroll
        for (int ks = 0; ks < 2; ks++) {
            int row = mt * 16 + l15;
            int blk = (ks * 4 + quad) ^ (row & 7);
            xa[mt][ks]  = *(const bf16x8*)(xbS + row * 128 + blk * 16);
            yna[mt][ks] = *(const bf16x8*)(ynS + row * 128 + blk * 16);
        }
    __syncthreads();   // shared xbS/ynS dead; aliased P / q-k regions now usable

    f32x4 acc[2][4];
    #pragma unroll
    for (int mt = 0; mt < 2; mt++)
        #pragma unroll
        for (int nt = 0; nt < 4; nt++)
            acc[mt][nt] = (f32x4){0.f, 0.f, 0.f, 0.f};

    const f32x4 z4 = {0.f, 0.f, 0.f, 0.f};
    const bf16x8 z8 = {0, 0, 0, 0, 0, 0, 0, 0};
    const f32x16 z16 = {0.f,0.f,0.f,0.f,0.f,0.f,0.f,0.f,0.f,0.f,0.f,0.f,0.f,0.f,0.f,0.f};

    // FWT swizzle constants (16B block ^= (l15>>2)&3)
    const int sw4 = (l15 >> 2) & 3;
    unsigned char* w0p = fwb + ((((quad >> 1) ^ sw4)) << 4) + (quad & 1) * 8;
    unsigned char* w1p = fwb + (((((quad >> 1) ^ sw4)) ^ 2) << 4) + (quad & 1) * 8;
    unsigned char* brp = fwb + l15 * 64 + ((quad ^ sw4) << 4);

    const int uc = (r32 < 25) ? r32 : 24;   // clamped topo row

    // in-register softmax + P store (verified r5 layout). dd: lane r32 = row u;
    // v(r) = (r&3)+8*(r>>2)+4*hi.
    auto softmax_store = [&](f32x16& dd, const float* tp, unsigned char* Pb) {
        dd[12] = hi ? -3e30f : dd[12];
        dd[13] = -3e30f; dd[14] = -3e30f; dd[15] = -3e30f;
        float t8[8];
        #pragma unroll
        for (int r = 0; r < 8; r++) t8[r] = fmaxf(dd[r], dd[r + 8]);
        #pragma unroll
        for (int r = 0; r < 4; r++) t8[r] = fmaxf(t8[r], t8[r + 4]);
        float m = fmaxf(fmaxf(t8[0], t8[1]), fmaxf(t8[2], t8[3]));
        m = fmaxf(m, __shfl_xor(m, 32));
        float s0 = 0.f, s1 = 0.f, s2 = 0.f, s3 = 0.f;
        #pragma unroll
        for (int r = 0; r < 16; r += 4) {
            dd[r]     = __builtin_amdgcn_exp2f(dd[r] - m);     s0 += dd[r];
            dd[r + 1] = __builtin_amdgcn_exp2f(dd[r + 1] - m); s1 += dd[r + 1];
            dd[r + 2] = __builtin_amdgcn_exp2f(dd[r + 2] - m); s2 += dd[r + 2];
            dd[r + 3] = __builtin_amdgcn_exp2f(dd[r + 3] - m); s3 += dd[r + 3];
        }
        float s = (s0 + s1) + (s2 + s3);
        s += __shfl_xor(s, 32);
        float inv = __builtin_amdgcn_rcpf(s);
        #pragma unroll
        for (int r = 0; r < 16; r++) dd[r] = dd[r] * inv * tp[r];
        if (r32 < 25) {
            unsigned char* rowp = Pb + r32 * 80 + hi * 8;
            *(i32x2*)(rowp +  0) = (i32x2){pack2(dd[0], dd[1]),   pack2(dd[2], dd[3])};
            *(i32x2*)(rowp + 16) = (i32x2){pack2(dd[4], dd[5]),   pack2(dd[6], dd[7])};
            *(i32x2*)(rowp + 32) = (i32x2){pack2(dd[8], dd[9]),   pack2(dd[10], dd[11])};
            *(i32x2*)(rowp + 48) = (i32x2){pack2(dd[12], dd[13]), pack2(dd[14], dd[15])};
        }
    };

    auto topo_gather = [&](int h, float (&tp)[16]) {
        const float* tb = topo + h * 625 + uc * 25 + hi * 4;
        #pragma unroll
        for (int r = 0; r < 16; r++) {
            int off = (r < 12) ? ((r & 3) + (r >> 2) * 8)
                    : (r == 12 ? (hi ? 0 : 24) : 0);   // pad offsets clamped in-bounds
            tp[r] = tb[off];
        }
    };

    // ---- this wave's single head-pair (r7 body) ----
    #pragma unroll
    for (int tsel = 0; tsel < 2; tsel++) {
        int nt = tsel ? (4 + hp) : hp;
        bf16x8 b0 = *(const bf16x8*)&wqk[(nt * 2 + 0) * 512 + lane * 8];
        bf16x8 b1 = *(const bf16x8*)&wqk[(nt * 2 + 1) * 512 + lane * 8];
        float bias = b_qk[(tsel ? 64 : 0) + hp * 16 + l15];
        unsigned short* buf = tsel ? kbuf : qbuf;
        #pragma unroll
        for (int mt = 0; mt < 2; mt++) {
            f32x4 d = MFMA16(yna[mt][0], b0, z4);
            d = MFMA16(yna[mt][1], b1, d);
            #pragma unroll
            for (int r = 0; r < 4; r++) {
                int u = mt * 16 + quad * 4 + r;
                if (u < 25) {
                    float val = d[r] + bias;
                    if (!tsel) val *= SCALE_L2E;
                    buf[u * 24 + l15] = bfh(val);
                }
            }
        }
    }

    float tp0[16];
    topo_gather(hp * 2, tp0);
    LGKM0();   // q/k visible

    f32x16 p0, p1;
    {
        bf16x8 ak = z8, bq = z8;
        if (hi == 0) {
            ak = *(const bf16x8*)&kbuf[r32 * 24 + 0];
            bq = *(const bf16x8*)&qbuf[r32 * 24 + 0];
        }
        p0 = __builtin_amdgcn_mfma_f32_32x32x16_bf16(ak, bq, z16, 0, 0, 0);
    }
    float tp1[16];
    topo_gather(hp * 2 + 1, tp1);
    {
        bf16x8 ak = z8, bq = z8;
        if (hi == 0) {
            ak = *(const bf16x8*)&kbuf[r32 * 24 + 8];
            bq = *(const bf16x8*)&qbuf[r32 * 24 + 8];
        }
        p1 = __builtin_amdgcn_mfma_f32_32x32x16_bf16(ak, bq, z16, 0, 0, 0);
    }
    softmax_store(p0, tp0, pb0);
    softmax_store(p1, tp1, pb1);

    // FW hh=0 (overlays q/k after dots reads; same-wave DS ordering)
    bf16x8 w2e[8];
    #pragma unroll
    for (int nt = 0; nt < 4; nt++) {
        int h = hp * 2;
        w2e[2 * nt]     = *(const bf16x8*)&w2f[((h * 4 + nt) * 2 + 0) * 512 + lane * 8];
        w2e[2 * nt + 1] = *(const bf16x8*)&w2f[((h * 4 + nt) * 2 + 1) * 512 + lane * 8];
    }
    #pragma unroll
    for (int nt = 0; nt < 4; nt++) {
        f32x4 dw0 = MFMA16(xa[0][0], w2e[2 * nt], z4);
        dw0 = MFMA16(xa[0][1], w2e[2 * nt + 1], dw0);
        f32x4 dw1 = MFMA16(xa[1][0], w2e[2 * nt], z4);
        dw1 = MFMA16(xa[1][1], w2e[2 * nt + 1], dw1);
        i32x2 q0 = {pack2(dw0[0], dw0[1]), pack2(dw0[2], dw0[3])};
        i32x2 q1 = {pack2(dw1[0], dw1[1]), pack2(dw1[2], dw1[3])};
        *(i32x2*)(w0p + nt * 1024 + l15 * 64) = q0;
        *(i32x2*)(w1p + nt * 1024 + l15 * 64) = q1;
    }
    bf16x8 w2o[8];
    #pragma unroll
    for (int nt = 0; nt < 4; nt++) {
        int h = hp * 2 + 1;
        w2o[2 * nt]     = *(const bf16x8*)&w2f[((h * 4 + nt) * 2 + 0) * 512 + lane * 8];
        w2o[2 * nt + 1] = *(const bf16x8*)&w2f[((h * 4 + nt) * 2 + 1) * 512 + lane * 8];
    }
    LGKM0();   // P0/P1 + FWT(hh=0) visible

    // PV hh=0
    {
        bf16x8 ag0 = *(const bf16x8*)(pb0 + l15 * 80 + quad * 16);
        bf16x8 ag1 = *(const bf16x8*)(pb0 + 1280 + l15 * 80 + quad * 16);
        #pragma unroll
        for (int nt = 0; nt < 4; nt++) {
            bf16x8 br = *(const bf16x8*)(brp + nt * 1024);
            acc[0][nt] = MFMA16(ag0, br, acc[0][nt]);
            acc[1][nt] = MFMA16(ag1, br, acc[1][nt]);
        }
    }

    // FW hh=1 -> FWT (after PV0 reads)
    #pragma unroll
    for (int nt = 0; nt < 4; nt++) {
        f32x4 dw0 = MFMA16(xa[0][0], w2o[2 * nt], z4);
        dw0 = MFMA16(xa[0][1], w2o[2 * nt + 1], dw0);
        f32x4 dw1 = MFMA16(xa[1][0], w2o[2 * nt], z4);
        dw1 = MFMA16(xa[1][1], w2o[2 * nt + 1], dw1);
        i32x2 q0 = {pack2(dw0[0], dw0[1]), pack2(dw0[2], dw0[3])};
        i32x2 q1 = {pack2(dw1[0], dw1[1]), pack2(dw1[2], dw1[3])};
        *(i32x2*)(w0p + nt * 1024 + l15 * 64) = q0;
        *(i32x2*)(w1p + nt * 1024 + l15 * 64) = q1;
    }
    LGKM0();   // FWT(hh=1) visible

    // PV hh=1
    {
        bf16x8 ag0 = *(const bf16x8*)(pb1 + l15 * 80 + quad * 16);
        bf16x8 ag1 = *(const bf16x8*)(pb1 + 1280 + l15 * 80 + quad * 16);
        #pragma unroll
        for (int nt = 0; nt < 4; nt++) {
            bf16x8 br = *(const bf16x8*)(brp + nt * 1024);
            acc[0][nt] = MFMA16(ag0, br, acc[0][nt]);
            acc[1][nt] = MFMA16(ag1, br, acc[1][nt]);
        }
    }

    // ---- cross-wave reduction: red[w][o][u] = 4 x 64 x 36 floats (36864 B) ----
    __syncthreads();                       // all wave-private LDS use done
    {
        float* red = (float*)smem + wv * 2304;
        #pragma unroll
        for (int mt = 0; mt < 2; mt++)
            #pragma unroll
            for (int nt = 0; nt < 4; nt++)
                *(f32x4*)&red[(nt * 16 + l15) * 36 + mt * 16 + quad * 4] = acc[mt][nt];
    }
    __syncthreads();

    // ---- epilogue: wave wv handles o in [wv*16, wv*16+16) ----
    {
        const float* redf = (const float*)smem;
        const int o = wv * 16 + l15;
        const float gA = bnA[o], gB = bnB[o];
        const float* xo = xg + (size_t)o * 6400;
        float* oo = og + (size_t)o * 6400;
        #pragma unroll
        for (int mt = 0; mt < 2; mt++) {
            const int ub = mt * 16 + quad * 4;
            f32x4 s = {0.f, 0.f, 0.f, 0.f};
            #pragma unroll
            for (int w = 0; w < 4; w++)
                s += *(const f32x4*)&redf[w * 2304 + o * 36 + ub];
            if (ub + 3 < 25) {
                f32x4 xr = *(const f32x4*)&xo[ub];
                f32x4 v;
                #pragma unroll
                for (int r = 0; r < 4; r++) v[r] = fmaxf(s[r] * gA + gB + xr[r], 0.f);
                *(f32x4*)&oo[ub] = v;
            } else if (ub < 25) {   // ub == 24
                oo[ub] = fmaxf(s[0] * gA + gB + xo[ub], 0.f);
            }
        }
    }
}

extern "C" void kernel_launch(void* const* d_in, const int* in_sizes, int n_in,
                              void* d_out, int out_size, void* d_ws, size_t ws_size,
                              hipStream_t stream) {
    const float* x      = (const float*)d_in[0];
    const float* ln_g   = (const float*)d_in[1];
    const float* ln_b   = (const float*)d_in[2];
    const float* w_qk   = (const float*)d_in[3];
    const float* b_qk   = (const float*)d_in[4];
    const float* topo   = (const float*)d_in[5];
    const float* conv_w = (const float*)d_in[6];
    const float* conv_b = (const float*)d_in[7];
    const float* bn_g   = (const float*)d_in[8];
    const float* bn_b   = (const float*)d_in[9];
    const float* bn_m   = (const float*)d_in[10];
    const float* bn_v   = (const float*)d_in[11];
    float* outp = (float*)d_out;
    unsigned short* wsp = (unsigned short*)d_ws;

    hipLaunchKernelGGL(prep_kernel, dim3(161), dim3(256), 0, stream,
                       w_qk, conv_w, conv_b, bn_g, bn_b, bn_m, bn_v, wsp);
    hipLaunchKernelGGL(sagc_kernel, dim3(8192), dim3(256), 0, stream,
                       x, ln_g, ln_b, b_qk, topo, (const unsigned short*)wsp, outp);
}